// Round 1
// baseline (673.367 us; speedup 1.0000x reference)
//
#include <hip/hip_runtime.h>

// VertexSplitter: B=256, V=512.
// out = (M > 0) where M = (Pid > 0) with 8 per-batch conditional edits.
// Output is (out, out) concatenated -> 2 * B*V*V floats.

#define BATCH 256
#define VDIM 512

__global__ void __launch_bounds__(256) fill_kernel(const float4* __restrict__ pid,
                                                   float4* __restrict__ out,
                                                   long long n4) {
    long long i = (long long)blockIdx.x * blockDim.x + threadIdx.x;
    if (i >= n4) return;
    float4 p = pid[i];
    float4 o;
    o.x = p.x > 0.f ? 1.f : 0.f;
    o.y = p.y > 0.f ? 1.f : 0.f;
    o.z = p.z > 0.f ? 1.f : 0.f;
    o.w = p.w > 0.f ? 1.f : 0.f;
    out[i]      = o;   // first output copy
    out[i + n4] = o;   // second output copy (tuple returns (out, out))
}

__global__ void __launch_bounds__(256) edit_kernel(const float* __restrict__ pid,
                                                   const int* __restrict__ inter,
                                                   float* __restrict__ out,
                                                   long long n) {
    int b = blockIdx.x * blockDim.x + threadIdx.x;
    if (b >= BATCH) return;

    int e10 = inter[b * 4 + 0];
    int e11 = inter[b * 4 + 1];
    int e20 = inter[b * 4 + 2];
    int e21 = inter[b * 4 + 3];

    bool distinct = (e10 != e11) && (e10 != e20) && (e10 != e21) &&
                    (e11 != e20) && (e11 != e21) && (e20 != e21);

    const float* P = pid + (long long)b * VDIM * VDIM;
    // blocked / old_pid read from ORIGINAL M = (Pid > 0), before any edits
    bool blocked = (P[(long long)e10 * VDIM + e20] > 0.f) ||
                   (P[(long long)e11 * VDIM + e21] > 0.f);
    bool valid = distinct && !blocked;
    if (!valid) return;

    float old_pid = (P[(long long)e10 * VDIM + e11] > 0.f) ? 1.f : 0.f;

    float* O0 = out + (long long)b * VDIM * VDIM;
    float* O1 = O0 + n;

    // All 8 ordered positions are distinct when valid (4 distinct vertices),
    // so the sequential csets reduce to independent stores.
    long long i_1011 = (long long)e10 * VDIM + e11;
    long long i_1110 = (long long)e11 * VDIM + e10;
    long long i_2021 = (long long)e20 * VDIM + e21;
    long long i_2120 = (long long)e21 * VDIM + e20;
    long long i_1020 = (long long)e10 * VDIM + e20;
    long long i_2010 = (long long)e20 * VDIM + e10;
    long long i_1121 = (long long)e11 * VDIM + e21;
    long long i_2111 = (long long)e21 * VDIM + e11;

    O0[i_1011] = 0.f;      O1[i_1011] = 0.f;
    O0[i_1110] = 0.f;      O1[i_1110] = 0.f;
    O0[i_2021] = 0.f;      O1[i_2021] = 0.f;
    O0[i_2120] = 0.f;      O1[i_2120] = 0.f;
    O0[i_1020] = old_pid;  O1[i_1020] = old_pid;
    O0[i_2010] = old_pid;  O1[i_2010] = old_pid;
    O0[i_1121] = 1.f;      O1[i_1121] = 1.f;
    O0[i_2111] = 1.f;      O1[i_2111] = 1.f;
}

extern "C" void kernel_launch(void* const* d_in, const int* in_sizes, int n_in,
                              void* d_out, int out_size, void* d_ws, size_t ws_size,
                              hipStream_t stream) {
    const float* pid  = (const float*)d_in[0];   // (B, V, V) float32
    const int* inter  = (const int*)d_in[1];     // (B, 2, 2) int32
    float* out        = (float*)d_out;           // 2 * B*V*V float32

    long long n  = (long long)BATCH * VDIM * VDIM;  // 67,108,864
    long long n4 = n / 4;                           // 16,777,216 float4s

    dim3 block(256);
    dim3 grid((unsigned)((n4 + 255) / 256));        // 65,536 blocks
    fill_kernel<<<grid, block, 0, stream>>>((const float4*)pid, (float4*)out, n4);
    edit_kernel<<<1, 256, 0, stream>>>(pid, inter, out, n);
}